// Round 1
// baseline (1919.339 us; speedup 1.0000x reference)
//
#include <hip/hip_runtime.h>
#include <math.h>

#define BATCH 8
#define DIM   512
#define NPTS  2048
#define KNN   10
#define NPAIR 45

constexpr int RN = 32;   // rows (n) per block in score kernel
constexpr int CM = 64;   // cols (m) per tile
constexpr int KC = 32;   // k chunk

// ---------------------------------------------------------------------------
// Kernel A: scores = src_emb^T tgt_emb / sqrt(512); fused softmax(10000*s),
// argmax (corres), and corr_tgt = softmax @ tgt^T   (flash-style online)
// ---------------------------------------------------------------------------
__global__ __launch_bounds__(256)
void score_kernel(const float* __restrict__ se, const float* __restrict__ te,
                  const float* __restrict__ tgt,
                  float* __restrict__ corr_tgt, int* __restrict__ corres_i,
                  float* __restrict__ corres_out)
{
    const int b  = blockIdx.x / (NPTS / RN);
    const int n0 = (blockIdx.x % (NPTS / RN)) * RN;
    const int t  = threadIdx.x;
    const int tr = t & 15;     // row group: rows {tr, tr+16}
    const int tc = t >> 4;     // col group: cols {4tc..4tc+3}

    __shared__ float As[KC][RN];
    __shared__ float Bs[KC][CM];
    __shared__ float tgtS[3][CM];
    __shared__ float redv[RN][16];
    __shared__ int   redi[RN][16];
    __shared__ float part[RN][16][4];
    __shared__ float rowmax[RN], rowsum[RN], rowfac[RN], rowacc[RN][3];
    __shared__ int   rowarg[RN];

    if (t < RN) {
        rowmax[t] = -3.402823466e38f;
        rowsum[t] = 0.f; rowarg[t] = 0;
        rowacc[t][0] = rowacc[t][1] = rowacc[t][2] = 0.f;
    }

    const float* A  = se + (size_t)b * DIM * NPTS;
    const float* Bp = te + (size_t)b * DIM * NPTS;
    const float sqd = sqrtf((float)DIM);

    for (int m0 = 0; m0 < NPTS; m0 += CM) {
        __syncthreads();
        if (t < 3 * CM) {
            int k = t / CM, c = t % CM;
            tgtS[k][c] = tgt[((size_t)b * 3 + k) * NPTS + m0 + c];
        }
        float acc[2][4] = {{0.f,0.f,0.f,0.f},{0.f,0.f,0.f,0.f}};
        for (int k0 = 0; k0 < DIM; k0 += KC) {
            __syncthreads();
            #pragma unroll
            for (int i = 0; i < 4; ++i) {              // KC*RN/256
                int idx = t + i * 256;
                As[idx >> 5][idx & 31] = A[(size_t)(k0 + (idx >> 5)) * NPTS + n0 + (idx & 31)];
            }
            #pragma unroll
            for (int i = 0; i < 8; ++i) {              // KC*CM/256
                int idx = t + i * 256;
                Bs[idx >> 6][idx & 63] = Bp[(size_t)(k0 + (idx >> 6)) * NPTS + m0 + (idx & 63)];
            }
            __syncthreads();
            #pragma unroll
            for (int kk = 0; kk < KC; ++kk) {
                float a0 = As[kk][tr], a1 = As[kk][tr + 16];
                float4 bb = *((const float4*)&Bs[kk][tc << 2]);
                acc[0][0] += a0 * bb.x; acc[0][1] += a0 * bb.y;
                acc[0][2] += a0 * bb.z; acc[0][3] += a0 * bb.w;
                acc[1][0] += a1 * bb.x; acc[1][1] += a1 * bb.y;
                acc[1][2] += a1 * bb.z; acc[1][3] += a1 * bb.w;
            }
        }
        // ---- online softmax update for this m-tile ----
        float u[2][4];
        #pragma unroll
        for (int rr = 0; rr < 2; ++rr) {
            int r = tr + rr * 16;
            float lmax = -3.402823466e38f; int larg = 0;
            #pragma unroll
            for (int j = 0; j < 4; ++j) {
                float s  = acc[rr][j] / sqd;
                float uu = 10000.0f * s;
                u[rr][j] = uu;
                if (uu > lmax) { lmax = uu; larg = m0 + tc * 4 + j; }
            }
            redv[r][tc] = lmax; redi[r][tc] = larg;
        }
        __syncthreads();
        if (t < RN) {
            float tmax = -3.402823466e38f; int targ = 0;
            #pragma unroll
            for (int c = 0; c < 16; ++c) {     // ascending m: first-index ties
                if (redv[t][c] > tmax) { tmax = redv[t][c]; targ = redi[t][c]; }
            }
            float om = rowmax[t];
            float nm = om > tmax ? om : tmax;
            if (tmax > om) rowarg[t] = targ;   // strict >: keep earlier m on tie
            rowfac[t] = expf(om - nm);
            rowmax[t] = nm;
        }
        __syncthreads();
        #pragma unroll
        for (int rr = 0; rr < 2; ++rr) {
            int r = tr + rr * 16;
            float nm = rowmax[r];
            float ps = 0.f, px = 0.f, py = 0.f, pz = 0.f;
            #pragma unroll
            for (int j = 0; j < 4; ++j) {
                float p = expf(u[rr][j] - nm);
                int c = tc * 4 + j;
                ps += p; px += p * tgtS[0][c]; py += p * tgtS[1][c]; pz += p * tgtS[2][c];
            }
            part[r][tc][0] = ps; part[r][tc][1] = px;
            part[r][tc][2] = py; part[r][tc][3] = pz;
        }
        __syncthreads();
        if (t < RN) {
            float f  = rowfac[t];
            float s  = rowsum[t] * f;
            float ax = rowacc[t][0] * f, ay = rowacc[t][1] * f, az = rowacc[t][2] * f;
            for (int c = 0; c < 16; ++c) {
                s  += part[t][c][0];
                ax += part[t][c][1]; ay += part[t][c][2]; az += part[t][c][3];
            }
            rowsum[t] = s; rowacc[t][0] = ax; rowacc[t][1] = ay; rowacc[t][2] = az;
        }
    }
    __syncthreads();
    if (t < RN) {
        int n = n0 + t;
        size_t o = (size_t)b * NPTS + n;
        float inv = rowsum[t];
        corr_tgt[o * 3 + 0] = rowacc[t][0] / inv;
        corr_tgt[o * 3 + 1] = rowacc[t][1] / inv;
        corr_tgt[o * 3 + 2] = rowacc[t][2] / inv;
        corres_i[o]   = rowarg[t];
        corres_out[o] = (float)rowarg[t];
    }
}

// ---------------------------------------------------------------------------
// Kernel B: GFM — knn(10) by w=exp(-d2/2) (stable ties), 45 triangles,
// loss/reg/median machinery -> mean_loss per (b,n)
// ---------------------------------------------------------------------------
__device__ inline void isort45(float* a) {
    for (int i = 1; i < NPAIR; ++i) {
        float key = a[i]; int j = i - 1;
        while (j >= 0 && a[j] > key) { a[j + 1] = a[j]; --j; }
        a[j + 1] = key;
    }
}

__global__ __launch_bounds__(256)
void gfm_kernel(const float* __restrict__ src, const float* __restrict__ corr_tgt,
                float* __restrict__ mean_loss)
{
    const int b  = blockIdx.x >> 3;
    const int n0 = (blockIdx.x & 7) * 256;
    const int t  = threadIdx.x;
    __shared__ float P[NPTS][3];
    __shared__ float CT[NPTS][3];
    __shared__ float SQ[NPTS];
    for (int i = t; i < NPTS; i += 256) {
        float x = src[((size_t)b * 3 + 0) * NPTS + i];
        float y = src[((size_t)b * 3 + 1) * NPTS + i];
        float z = src[((size_t)b * 3 + 2) * NPTS + i];
        P[i][0] = x; P[i][1] = y; P[i][2] = z;
        SQ[i] = x * x + y * y + z * z;
        size_t o = ((size_t)b * NPTS + i) * 3;
        CT[i][0] = corr_tgt[o + 0]; CT[i][1] = corr_tgt[o + 1]; CT[i][2] = corr_tgt[o + 2];
    }
    __syncthreads();
    const int n = n0 + t;
    const float pnx = P[n][0], pny = P[n][1], pnz = P[n][2];
    const float sqn = SQ[n];

    float wl[KNN]; int il[KNN];
    #pragma unroll
    for (int k = 0; k < KNN; ++k) { wl[k] = -1.f; il[k] = 0; }

    for (int m = 0; m < NPTS; ++m) {
        float dot = pnx * P[m][0] + pny * P[m][1] + pnz * P[m][2];
        float d2 = (sqn + SQ[m]) - 2.0f * dot;
        if (d2 < 0.f) d2 = 0.f;
        float w = expf(-d2 * 0.5f);
        if (w > wl[KNN - 1]) {                 // strict: jax top_k stable ties
            float cw = w; int ci = m;
            #pragma unroll
            for (int k = 0; k < KNN; ++k) {
                if (cw > wl[k]) {
                    float tv = wl[k]; wl[k] = cw; cw = tv;
                    int ti = il[k]; il[k] = ci; ci = ti;
                }
            }
        }
    }

    float kx[KNN], ky[KNN], kz[KNN], tx[KNN], ty[KNN], tz[KNN];
    #pragma unroll
    for (int k = 0; k < KNN; ++k) {
        int id = il[k];
        kx[k] = P[id][0]; ky[k] = P[id][1]; kz[k] = P[id][2];
        tx[k] = CT[id][0]; ty[k] = CT[id][1]; tz[k] = CT[id][2];
    }
    const float cnx = CT[n][0], cny = CT[n][1], cnz = CT[n][2];

    float ls[NPAIR], rg[NPAIR];
    int q = 0;
    #pragma unroll
    for (int i = 0; i < KNN - 1; ++i) {
        #pragma unroll
        for (int j = i + 1; j < KNN; ++j) {
            float e1x = kx[i] - pnx, e1y = ky[i] - pny, e1z = kz[i] - pnz;
            float e2x = kx[j] - pnx, e2y = ky[j] - pny, e2z = kz[j] - pnz;
            float cx = e1y * e2z - e1z * e2y;
            float cy = e1z * e2x - e1x * e2z;
            float cz = e1x * e2y - e1y * e2x;
            float as_ = 0.5f * sqrtf(cx * cx + cy * cy + cz * cz);
            float f1x = tx[i] - cnx, f1y = ty[i] - cny, f1z = tz[i] - cnz;
            float f2x = tx[j] - cnx, f2y = ty[j] - cny, f2z = tz[j] - cnz;
            float gx = f1y * f2z - f1z * f2y;
            float gy = f1z * f2x - f1x * f2z;
            float gz = f1x * f2y - f1y * f2x;
            float at_ = 0.5f * sqrtf(gx * gx + gy * gy + gz * gz);
            float tl2 = at_ + 1e-6f;           // tl = [eps, eps, at+eps]
            float dd  = as_ - tl2;             // sl = [0, 0, as]
            float e2_ = 1e-6f * 1e-6f;
            float num = (e2_ + e2_) + dd * dd;
            float den = (1e-6f + 1e-6f) + (as_ + tl2);
            ls[q] = num / den;
            rg[q] = sqrtf(num);
            ++q;
        }
    }
    float srt[NPAIR], tot[NPAIR], tmp[NPAIR];
    for (int k = 0; k < NPAIR; ++k) srt[k] = ls[k];
    isort45(srt);
    for (int k = 0; k < NPAIR; ++k) { tot[k] = srt[k] + 0.1f * rg[k]; tmp[k] = tot[k]; }
    isort45(tmp);
    float thr = 3.0f * tmp[22];
    float accv = 0.f;
    for (int k = 0; k < KNN; ++k) {
        float v = tot[k];
        v = (v > thr) ? 0.0f : v;
        accv += sqrtf(v + 1e-6f);
    }
    mean_loss[(size_t)b * NPTS + n] = accv / 10.0f;
}

// ---------------------------------------------------------------------------
// Kernel C: per-batch min of mean_loss; weight = (2*sigmoid(-20*(ml-min)) > .5)
// ---------------------------------------------------------------------------
__global__ __launch_bounds__(256)
void weight_kernel(const float* __restrict__ mean_loss, float* __restrict__ weight_out)
{
    const int b = blockIdx.x;
    const int t = threadIdx.x;
    __shared__ float red[256];
    float mn = 3.402823466e38f;
    for (int i = t; i < NPTS; i += 256)
        mn = fminf(mn, mean_loss[(size_t)b * NPTS + i]);
    red[t] = mn; __syncthreads();
    for (int s2 = 128; s2 > 0; s2 >>= 1) {
        if (t < s2) red[t] = fminf(red[t], red[t + s2]);
        __syncthreads();
    }
    float ml = red[0];
    for (int i = t; i < NPTS; i += 256) {
        float d = mean_loss[(size_t)b * NPTS + i] - ml;
        float e = expf(-20.0f * d);            // x<=0 branch of jax sigmoid
        float wts = 2.0f * (e / (1.0f + e));
        weight_out[(size_t)b * NPTS + i] = (wts > 0.5f) ? 1.0f : 0.0f;
    }
}

// ---------------------------------------------------------------------------
// Kernel D: weighted Procrustes per batch (Horn quaternion == Kabsch SVD+sign)
// ---------------------------------------------------------------------------
__device__ void jacobi4(double A[4][4], double V[4][4]) {
    for (int i = 0; i < 4; ++i)
        for (int j = 0; j < 4; ++j) V[i][j] = (i == j) ? 1.0 : 0.0;
    for (int sweep = 0; sweep < 30; ++sweep) {
        for (int p = 0; p < 3; ++p) for (int q = p + 1; q < 4; ++q) {
            double apq = A[p][q];
            if (fabs(apq) < 1e-30) continue;
            double theta = (A[q][q] - A[p][p]) / (2.0 * apq);
            double tt = (theta >= 0 ? 1.0 : -1.0) / (fabs(theta) + sqrt(theta * theta + 1.0));
            double c = 1.0 / sqrt(tt * tt + 1.0), s = tt * c;
            for (int k = 0; k < 4; ++k) {
                double akp = A[k][p], akq = A[k][q];
                A[k][p] = c * akp - s * akq;
                A[k][q] = s * akp + c * akq;
            }
            for (int k = 0; k < 4; ++k) {
                double apk = A[p][k], aqk = A[q][k];
                A[p][k] = c * apk - s * aqk;
                A[q][k] = s * apk + c * aqk;
            }
            for (int k = 0; k < 4; ++k) {
                double vkp = V[k][p], vkq = V[k][q];
                V[k][p] = c * vkp - s * vkq;
                V[k][q] = s * vkp + c * vkq;
            }
        }
    }
}

__global__ __launch_bounds__(256)
void procrustes_kernel(const float* __restrict__ src, const float* __restrict__ tgt,
                       const int* __restrict__ corres_i, const float* __restrict__ weight,
                       float* __restrict__ outR, float* __restrict__ outT)
{
    const int b = blockIdx.x;
    const int t = threadIdx.x;
    __shared__ float red[256][9];
    __shared__ float s_tw, s_mx[3], s_my[3];
    __shared__ float s_cov[9];

    // pass 1: sums of w, w*X, w*Y
    float a0 = 0, a1 = 0, a2 = 0, a3 = 0, a4 = 0, a5 = 0, a6 = 0;
    for (int i = t; i < NPTS; i += 256) {
        float w = weight[(size_t)b * NPTS + i];
        float X0 = src[((size_t)b * 3 + 0) * NPTS + i];
        float X1 = src[((size_t)b * 3 + 1) * NPTS + i];
        float X2 = src[((size_t)b * 3 + 2) * NPTS + i];
        int c = corres_i[(size_t)b * NPTS + i];
        float Y0 = tgt[((size_t)b * 3 + 0) * NPTS + c];
        float Y1 = tgt[((size_t)b * 3 + 1) * NPTS + c];
        float Y2 = tgt[((size_t)b * 3 + 2) * NPTS + c];
        a0 += w;
        a1 += w * X0; a2 += w * X1; a3 += w * X2;
        a4 += w * Y0; a5 += w * Y1; a6 += w * Y2;
    }
    red[t][0] = a0; red[t][1] = a1; red[t][2] = a2; red[t][3] = a3;
    red[t][4] = a4; red[t][5] = a5; red[t][6] = a6; red[t][7] = 0; red[t][8] = 0;
    __syncthreads();
    for (int s2 = 128; s2 > 0; s2 >>= 1) {
        if (t < s2)
            for (int k = 0; k < 7; ++k) red[t][k] += red[t + s2][k];
        __syncthreads();
    }
    if (t == 0) {
        float tw = red[0][0];
        float itw = tw + 1e-7f;
        s_tw = tw;
        s_mx[0] = red[0][1] / itw; s_mx[1] = red[0][2] / itw; s_mx[2] = red[0][3] / itw;
        s_my[0] = red[0][4] / itw; s_my[1] = red[0][5] / itw; s_my[2] = red[0][6] / itw;
    }
    __syncthreads();
    const float twp = s_tw + 1e-7f;
    const float mx0 = s_mx[0], mx1 = s_mx[1], mx2 = s_mx[2];
    const float my0 = s_my[0], my1 = s_my[1], my2 = s_my[2];

    // pass 2: cov[i][j] = sum (Y_i - my_i) * (w/(tw+eps)) * (X_j - mx_j)
    float cv[9] = {0,0,0,0,0,0,0,0,0};
    for (int i = t; i < NPTS; i += 256) {
        float w = weight[(size_t)b * NPTS + i];
        float nwn = w / twp;
        float X0 = src[((size_t)b * 3 + 0) * NPTS + i] - mx0;
        float X1 = src[((size_t)b * 3 + 1) * NPTS + i] - mx1;
        float X2 = src[((size_t)b * 3 + 2) * NPTS + i] - mx2;
        int c = corres_i[(size_t)b * NPTS + i];
        float Y0 = tgt[((size_t)b * 3 + 0) * NPTS + c] - my0;
        float Y1 = tgt[((size_t)b * 3 + 1) * NPTS + c] - my1;
        float Y2 = tgt[((size_t)b * 3 + 2) * NPTS + c] - my2;
        float b0 = nwn * X0, b1 = nwn * X1, b2 = nwn * X2;
        cv[0] += Y0 * b0; cv[1] += Y0 * b1; cv[2] += Y0 * b2;
        cv[3] += Y1 * b0; cv[4] += Y1 * b1; cv[5] += Y1 * b2;
        cv[6] += Y2 * b0; cv[7] += Y2 * b1; cv[8] += Y2 * b2;
    }
    __syncthreads();
    for (int k = 0; k < 9; ++k) red[t][k] = cv[k];
    __syncthreads();
    for (int s2 = 128; s2 > 0; s2 >>= 1) {
        if (t < s2)
            for (int k = 0; k < 9; ++k) red[t][k] += red[t + s2][k];
        __syncthreads();
    }
    if (t == 0) for (int k = 0; k < 9; ++k) s_cov[k] = red[0][k];
    __syncthreads();

    if (t == 0) {
        double cov[3][3];
        for (int i = 0; i < 3; ++i)
            for (int j = 0; j < 3; ++j) cov[i][j] = (double)s_cov[i * 3 + j];
        // S[a][b] = sum w * Xc_a * Yc_b = cov[b][a]
        double S[3][3];
        for (int a = 0; a < 3; ++a)
            for (int bb = 0; bb < 3; ++bb) S[a][bb] = cov[bb][a];
        double N4[4][4];
        N4[0][0] = S[0][0] + S[1][1] + S[2][2];
        N4[0][1] = S[1][2] - S[2][1];
        N4[0][2] = S[2][0] - S[0][2];
        N4[0][3] = S[0][1] - S[1][0];
        N4[1][1] = S[0][0] - S[1][1] - S[2][2];
        N4[1][2] = S[0][1] + S[1][0];
        N4[1][3] = S[2][0] + S[0][2];
        N4[2][2] = -S[0][0] + S[1][1] - S[2][2];
        N4[2][3] = S[1][2] + S[2][1];
        N4[3][3] = -S[0][0] - S[1][1] + S[2][2];
        N4[1][0] = N4[0][1]; N4[2][0] = N4[0][2]; N4[3][0] = N4[0][3];
        N4[2][1] = N4[1][2]; N4[3][1] = N4[1][3]; N4[3][2] = N4[2][3];
        double V[4][4];
        jacobi4(N4, V);
        int best = 0; double bl = N4[0][0];
        for (int k = 1; k < 4; ++k) if (N4[k][k] > bl) { bl = N4[k][k]; best = k; }
        double q0 = V[0][best], qx = V[1][best], qy = V[2][best], qz = V[3][best];
        double nq = sqrt(q0 * q0 + qx * qx + qy * qy + qz * qz);
        q0 /= nq; qx /= nq; qy /= nq; qz /= nq;
        double Rm[3][3];
        Rm[0][0] = q0*q0 + qx*qx - qy*qy - qz*qz;
        Rm[0][1] = 2.0 * (qx*qy - q0*qz);
        Rm[0][2] = 2.0 * (qx*qz + q0*qy);
        Rm[1][0] = 2.0 * (qx*qy + q0*qz);
        Rm[1][1] = q0*q0 - qx*qx + qy*qy - qz*qz;
        Rm[1][2] = 2.0 * (qy*qz - q0*qx);
        Rm[2][0] = 2.0 * (qx*qz - q0*qy);
        Rm[2][1] = 2.0 * (qy*qz + q0*qx);
        Rm[2][2] = q0*q0 - qx*qx - qy*qy + qz*qz;
        // deterministic convention safeguard: maximize trace(R cov^T)
        double o1 = 0, o2 = 0;
        for (int i = 0; i < 3; ++i)
            for (int j = 0; j < 3; ++j) { o1 += Rm[i][j] * cov[i][j]; o2 += Rm[j][i] * cov[i][j]; }
        if (o2 > o1) {
            for (int i = 0; i < 3; ++i)
                for (int j = i + 1; j < 3; ++j) {
                    double tv = Rm[i][j]; Rm[i][j] = Rm[j][i]; Rm[j][i] = tv;
                }
        }
        float Rf[3][3];
        for (int i = 0; i < 3; ++i)
            for (int j = 0; j < 3; ++j) {
                Rf[i][j] = (float)Rm[i][j];
                outR[(size_t)b * 9 + i * 3 + j] = Rf[i][j];
            }
        float rm[3];
        float mxv[3] = {mx0, mx1, mx2};
        float myv[3] = {my0, my1, my2};
        for (int i = 0; i < 3; ++i)
            rm[i] = Rf[i][0] * mxv[0] + Rf[i][1] * mxv[1] + Rf[i][2] * mxv[2];
        // T = my.reshape(3) - R@mx.T  -> (3,3) broadcast: T[i][j] = my[j]-rm[i]
        for (int i = 0; i < 3; ++i)
            for (int j = 0; j < 3; ++j)
                outT[(size_t)b * 9 + i * 3 + j] = myv[j] - rm[i];
    }
}

// ---------------------------------------------------------------------------
extern "C" void kernel_launch(void* const* d_in, const int* in_sizes, int n_in,
                              void* d_out, int out_size, void* d_ws, size_t ws_size,
                              hipStream_t stream)
{
    const float* se  = (const float*)d_in[0];
    const float* te  = (const float*)d_in[1];
    const float* src = (const float*)d_in[2];
    const float* tgt = (const float*)d_in[3];

    float* out  = (float*)d_out;
    float* outR = out;
    float* outT = out + 72;
    float* outC = out + 144;
    float* outW = out + 144 + BATCH * NPTS;

    char* wsb = (char*)d_ws;
    float* corr_tgt  = (float*)wsb;                                   // B*N*3 f32
    int*   corres_i  = (int*)(wsb + (size_t)BATCH * NPTS * 3 * 4);    // B*N i32
    float* mean_loss = (float*)(wsb + (size_t)BATCH * NPTS * 4 * 4);  // B*N f32

    hipLaunchKernelGGL(score_kernel, dim3(BATCH * (NPTS / RN)), dim3(256), 0, stream,
                       se, te, tgt, corr_tgt, corres_i, outC);
    hipLaunchKernelGGL(gfm_kernel, dim3(BATCH * (NPTS / 256)), dim3(256), 0, stream,
                       src, corr_tgt, mean_loss);
    hipLaunchKernelGGL(weight_kernel, dim3(BATCH), dim3(256), 0, stream,
                       mean_loss, outW);
    hipLaunchKernelGGL(procrustes_kernel, dim3(BATCH), dim3(256), 0, stream,
                       src, tgt, corres_i, outW, outR, outT);
}

// Round 2
// 1051.134 us; speedup vs baseline: 1.8260x; 1.8260x over previous
//
#include <hip/hip_runtime.h>
#include <math.h>

#define BATCH 8
#define DIM   512
#define NPTS  2048
#define KNN   10
#define NPAIR 45

// ===========================================================================
// Kernel A: scores GEMM + fused online softmax(10000*s), argmax, corr_tgt.
// grid = 8 batches * 32 row-tiles(64) * 2 m-chunks(1024) = 512 blocks, 256 thr
// per thread: 8 rows x 8 cols register tile; private online-softmax state;
// final merge across the 32 tc-lanes via shfl_xor; partial state -> ws.
// ===========================================================================
#define SK_ROWS 64
#define SK_MT   256
#define SK_KC   32
#define SK_NMT  4     // m-tiles per 1024-chunk
#define SK_NKC  16    // k-chunks (512/32)

__global__ __launch_bounds__(256)
void score_kernel(const float* __restrict__ se, const float* __restrict__ te,
                  const float* __restrict__ tgt, float* __restrict__ part)
{
    const int bid = blockIdx.x;
    const int b   = bid >> 6;
    const int rt  = (bid >> 1) & 31;
    const int mc  = bid & 1;
    const int n0  = rt * SK_ROWS;
    const int t   = threadIdx.x;
    const int tr  = t >> 5;      // 0..7  (rows tr*8..tr*8+7)
    const int tc  = t & 31;      // 0..31 (cols 2tc+jj*64+e)

    __shared__ float As[SK_KC][SK_ROWS];   // 8 KB
    __shared__ float Bs[SK_KC][SK_MT];     // 32 KB
    __shared__ float tgtS[3][SK_MT];       // 3 KB

    const float* A  = se + (size_t)b * DIM * NPTS;
    const float* Bp = te + (size_t)b * DIM * NPTS;
    const float sqd = sqrtf((float)DIM);

    float mx[8], sum[8], ax[8], ay[8], az[8];
    int   arg[8];
    #pragma unroll
    for (int r = 0; r < 8; ++r) {
        mx[r] = -3.402823466e38f; sum[r] = 0.f;
        ax[r] = 0.f; ay[r] = 0.f; az[r] = 0.f; arg[r] = 0;
    }

    for (int mt = 0; mt < SK_NMT; ++mt) {
        const int m0 = mc * 1024 + mt * SK_MT;
        __syncthreads();
        for (int i = t; i < 3 * SK_MT; i += 256)
            tgtS[i >> 8][i & 255] = tgt[((size_t)b * 3 + (i >> 8)) * NPTS + m0 + (i & 255)];

        float acc[8][8];
        #pragma unroll
        for (int r = 0; r < 8; ++r)
            #pragma unroll
            for (int c = 0; c < 8; ++c) acc[r][c] = 0.f;

        for (int kc = 0; kc < SK_NKC; ++kc) {
            const int k0 = kc * SK_KC;
            __syncthreads();
            #pragma unroll
            for (int p = 0; p < 2; ++p) {          // As: 512 float4
                int id = t + p * 256;
                int kk = id >> 4, c4 = id & 15;
                float4 v = *(const float4*)&A[(size_t)(k0 + kk) * NPTS + n0 + c4 * 4];
                *(float4*)&As[kk][c4 * 4] = v;
            }
            #pragma unroll
            for (int p = 0; p < 8; ++p) {          // Bs: 2048 float4
                int id = t + p * 256;
                int kk = id >> 6, c4 = id & 63;
                float4 v = *(const float4*)&Bp[(size_t)(k0 + kk) * NPTS + m0 + c4 * 4];
                *(float4*)&Bs[kk][c4 * 4] = v;
            }
            __syncthreads();
            #pragma unroll
            for (int kk = 0; kk < SK_KC; ++kk) {
                float4 af0 = *(const float4*)&As[kk][tr * 8];
                float4 af1 = *(const float4*)&As[kk][tr * 8 + 4];
                float a0[8] = {af0.x, af0.y, af0.z, af0.w, af1.x, af1.y, af1.z, af1.w};
                float2 bb[4];
                #pragma unroll
                for (int jj = 0; jj < 4; ++jj)
                    bb[jj] = *(const float2*)&Bs[kk][2 * tc + jj * 64];
                #pragma unroll
                for (int r = 0; r < 8; ++r) {
                    #pragma unroll
                    for (int jj = 0; jj < 4; ++jj) {
                        acc[r][2 * jj]     += a0[r] * bb[jj].x;
                        acc[r][2 * jj + 1] += a0[r] * bb[jj].y;
                    }
                }
            }
        }
        // ---- private online softmax update (cols ascending in (jj,e)) ----
        #pragma unroll
        for (int r = 0; r < 8; ++r) {
            float u[8];
            float lm = -3.402823466e38f; int la = 0;
            #pragma unroll
            for (int jj = 0; jj < 4; ++jj) {
                #pragma unroll
                for (int e = 0; e < 2; ++e) {
                    int ci = 2 * jj + e;
                    float s  = acc[r][ci] / sqd;
                    float uu = 10000.0f * s;
                    u[ci] = uu;
                    if (uu > lm) { lm = uu; la = m0 + 2 * tc + jj * 64 + e; }
                }
            }
            float nm = fmaxf(mx[r], lm);
            if (lm > mx[r]) arg[r] = la;
            float f = expf(mx[r] - nm);
            mx[r] = nm;
            float s_ = sum[r] * f, x_ = ax[r] * f, y_ = ay[r] * f, z_ = az[r] * f;
            #pragma unroll
            for (int jj = 0; jj < 4; ++jj) {
                #pragma unroll
                for (int e = 0; e < 2; ++e) {
                    int ci = 2 * jj + e;
                    float p = expf(u[ci] - nm);
                    int cc = 2 * tc + jj * 64 + e;
                    s_ += p;
                    x_ += p * tgtS[0][cc];
                    y_ += p * tgtS[1][cc];
                    z_ += p * tgtS[2][cc];
                }
            }
            sum[r] = s_; ax[r] = x_; ay[r] = y_; az[r] = z_;
        }
    }

    // ---- butterfly merge across the 32 tc-lanes ----
    #pragma unroll
    for (int r = 0; r < 8; ++r) {
        for (int mask = 1; mask < 32; mask <<= 1) {
            float omx  = __shfl_xor(mx[r],  mask);
            float osum = __shfl_xor(sum[r], mask);
            float oax  = __shfl_xor(ax[r],  mask);
            float oay  = __shfl_xor(ay[r],  mask);
            float oaz  = __shfl_xor(az[r],  mask);
            int   oarg = __shfl_xor(arg[r], mask);
            float nm = fmaxf(mx[r], omx);
            float f1 = expf(mx[r] - nm), f2 = expf(omx - nm);
            sum[r] = sum[r] * f1 + osum * f2;
            ax[r]  = ax[r]  * f1 + oax  * f2;
            ay[r]  = ay[r]  * f1 + oay  * f2;
            az[r]  = az[r]  * f1 + oaz  * f2;
            arg[r] = (omx > mx[r]) ? oarg : ((omx == mx[r]) ? min(arg[r], oarg) : arg[r]);
            mx[r]  = nm;
        }
    }
    if (tc == 0) {
        #pragma unroll
        for (int r = 0; r < 8; ++r) {
            int row = n0 + tr * 8 + r;
            size_t o = (((size_t)b * NPTS + row) * 2 + mc) * 8;
            part[o + 0] = mx[r];  part[o + 1] = sum[r];
            part[o + 2] = ax[r];  part[o + 3] = ay[r];  part[o + 4] = az[r];
            part[o + 5] = __int_as_float(arg[r]);
        }
    }
}

// ===========================================================================
// Kernel A2: merge the two m-chunk partial states per row.
// ===========================================================================
__global__ __launch_bounds__(256)
void merge_kernel(const float* __restrict__ part, float* __restrict__ corr_tgt,
                  int* __restrict__ corres_i, float* __restrict__ corres_out)
{
    int r = blockIdx.x * 256 + threadIdx.x;          // 0..16383
    size_t o0 = ((size_t)r * 2 + 0) * 8;
    size_t o1 = ((size_t)r * 2 + 1) * 8;
    float m1 = part[o0], s1 = part[o0 + 1], x1 = part[o0 + 2], y1 = part[o0 + 3], z1 = part[o0 + 4];
    int   a1 = __float_as_int(part[o0 + 5]);
    float m2 = part[o1], s2 = part[o1 + 1], x2 = part[o1 + 2], y2 = part[o1 + 3], z2 = part[o1 + 4];
    int   a2 = __float_as_int(part[o1 + 5]);
    float nm = fmaxf(m1, m2);
    float f1 = expf(m1 - nm), f2 = expf(m2 - nm);
    float s = s1 * f1 + s2 * f2;
    float x = x1 * f1 + x2 * f2;
    float y = y1 * f1 + y2 * f2;
    float z = z1 * f1 + z2 * f2;
    int a = (m2 > m1) ? a2 : a1;    // tie -> chunk 0 (lower index) ✓
    corr_tgt[(size_t)r * 3 + 0] = x / s;
    corr_tgt[(size_t)r * 3 + 1] = y / s;
    corr_tgt[(size_t)r * 3 + 2] = z / s;
    corres_i[r]   = a;
    corres_out[r] = (float)a;
}

// ===========================================================================
// Kernel B: GFM. 512-thread blocks, 64 n's x 8 m-chunks per block.
// ===========================================================================
#define GF_N  64
#define GF_C  8
#define GF_CS 256

__global__ __launch_bounds__(512)
void gfm_kernel(const float* __restrict__ src, const float* __restrict__ corr_tgt,
                float* __restrict__ mean_loss)
{
    const int b  = blockIdx.x >> 5;
    const int n0 = (blockIdx.x & 31) * GF_N;
    const int t  = threadIdx.x;
    __shared__ float4 P4[NPTS];              // x,y,z,|p|^2  32 KB
    __shared__ float  CT[NPTS][3];           // 24 KB
    __shared__ float  Lw[GF_N][GF_C][KNN];   // 20 KB
    __shared__ int    Li[GF_N][GF_C][KNN];   // 20 KB

    for (int i = t; i < NPTS; i += 512) {
        float x = src[((size_t)b * 3 + 0) * NPTS + i];
        float y = src[((size_t)b * 3 + 1) * NPTS + i];
        float z = src[((size_t)b * 3 + 2) * NPTS + i];
        P4[i] = make_float4(x, y, z, x * x + y * y + z * z);
        size_t o = ((size_t)b * NPTS + i) * 3;
        CT[i][0] = corr_tgt[o]; CT[i][1] = corr_tgt[o + 1]; CT[i][2] = corr_tgt[o + 2];
    }
    __syncthreads();

    {   // phase 2: per-(n, chunk) stable top-10
        const int nl = t & 63;
        const int c  = t >> 6;
        const int n  = n0 + nl;
        float4 pn = P4[n];
        float wl[KNN]; int il[KNN];
        #pragma unroll
        for (int k = 0; k < KNN; ++k) { wl[k] = -1.f; il[k] = 0; }
        const int mstart = c * GF_CS;
        for (int mm = 0; mm < GF_CS; ++mm) {
            int m = mstart + mm;
            float4 pm = P4[m];
            float dot = pn.x * pm.x + pn.y * pm.y + pn.z * pm.z;
            float d2  = (pn.w + pm.w) - 2.0f * dot;
            if (d2 < 0.f) d2 = 0.f;
            float w = expf(-d2 * 0.5f);
            if (w > wl[KNN - 1]) {
                float cw = w; int ci = m;
                #pragma unroll
                for (int k = 0; k < KNN; ++k) {
                    if (cw > wl[k]) {
                        float tv = wl[k]; wl[k] = cw; cw = tv;
                        int ti = il[k]; il[k] = ci; ci = ti;
                    }
                }
            }
        }
        #pragma unroll
        for (int k = 0; k < KNN; ++k) { Lw[nl][c][k] = wl[k]; Li[nl][c][k] = il[k]; }
    }
    __syncthreads();

    if (t < GF_N) {
        const int n = n0 + t;
        // stable 8-way merge (chunk order == index order on w-ties)
        int hp[GF_C];
        #pragma unroll
        for (int c = 0; c < GF_C; ++c) hp[c] = 0;
        int il[KNN];
        #pragma unroll
        for (int k = 0; k < KNN; ++k) {
            int bc = -1; float bw = 0.f;
            #pragma unroll
            for (int c = 0; c < GF_C; ++c) {
                if (hp[c] < KNN) {
                    float w = Lw[t][c][hp[c]];
                    if (bc < 0 || w > bw) { bw = w; bc = c; }
                }
            }
            il[k] = Li[t][bc][hp[bc]];
            hp[bc]++;
        }

        float4 pn = P4[n];
        const float pnx = pn.x, pny = pn.y, pnz = pn.z;
        float kx[KNN], ky[KNN], kz[KNN], tx[KNN], ty[KNN], tz[KNN];
        #pragma unroll
        for (int k = 0; k < KNN; ++k) {
            float4 pk = P4[il[k]];
            kx[k] = pk.x; ky[k] = pk.y; kz[k] = pk.z;
            tx[k] = CT[il[k]][0]; ty[k] = CT[il[k]][1]; tz[k] = CT[il[k]][2];
        }
        const float cnx = CT[n][0], cny = CT[n][1], cnz = CT[n][2];

        float ls[NPAIR], rg[NPAIR];
        int q = 0;
        #pragma unroll
        for (int i = 0; i < KNN - 1; ++i) {
            #pragma unroll
            for (int j = i + 1; j < KNN; ++j) {
                float e1x = kx[i] - pnx, e1y = ky[i] - pny, e1z = kz[i] - pnz;
                float e2x = kx[j] - pnx, e2y = ky[j] - pny, e2z = kz[j] - pnz;
                float cx = e1y * e2z - e1z * e2y;
                float cy = e1z * e2x - e1x * e2z;
                float cz = e1x * e2y - e1y * e2x;
                float as_ = 0.5f * sqrtf(cx * cx + cy * cy + cz * cz);
                float f1x = tx[i] - cnx, f1y = ty[i] - cny, f1z = tz[i] - cnz;
                float f2x = tx[j] - cnx, f2y = ty[j] - cny, f2z = tz[j] - cnz;
                float gx = f1y * f2z - f1z * f2y;
                float gy = f1z * f2x - f1x * f2z;
                float gz = f1x * f2y - f1y * f2x;
                float at_ = 0.5f * sqrtf(gx * gx + gy * gy + gz * gz);
                float tl2 = at_ + 1e-6f;
                float dd  = as_ - tl2;
                float e2_ = 1e-6f * 1e-6f;
                float num = (e2_ + e2_) + dd * dd;
                float den = (1e-6f + 1e-6f) + (as_ + tl2);
                ls[q] = num / den;
                rg[q] = sqrtf(num);
                ++q;
            }
        }
        float srt[NPAIR], tot[NPAIR], tmp[NPAIR];
        for (int k = 0; k < NPAIR; ++k) srt[k] = ls[k];
        for (int i = 1; i < NPAIR; ++i) {
            float key = srt[i]; int j = i - 1;
            while (j >= 0 && srt[j] > key) { srt[j + 1] = srt[j]; --j; }
            srt[j + 1] = key;
        }
        for (int k = 0; k < NPAIR; ++k) { tot[k] = srt[k] + 0.1f * rg[k]; tmp[k] = tot[k]; }
        for (int i = 1; i < NPAIR; ++i) {
            float key = tmp[i]; int j = i - 1;
            while (j >= 0 && tmp[j] > key) { tmp[j + 1] = tmp[j]; --j; }
            tmp[j + 1] = key;
        }
        float thr = 3.0f * tmp[22];
        float accv = 0.f;
        for (int k = 0; k < KNN; ++k) {
            float v = tot[k];
            v = (v > thr) ? 0.0f : v;
            accv += sqrtf(v + 1e-6f);
        }
        mean_loss[(size_t)b * NPTS + n] = accv / 10.0f;
    }
}

// ===========================================================================
// Kernel C: per-batch min + binary weight
// ===========================================================================
__global__ __launch_bounds__(256)
void weight_kernel(const float* __restrict__ mean_loss, float* __restrict__ weight_out)
{
    const int b = blockIdx.x;
    const int t = threadIdx.x;
    __shared__ float red[256];
    float mn = 3.402823466e38f;
    for (int i = t; i < NPTS; i += 256)
        mn = fminf(mn, mean_loss[(size_t)b * NPTS + i]);
    red[t] = mn; __syncthreads();
    for (int s2 = 128; s2 > 0; s2 >>= 1) {
        if (t < s2) red[t] = fminf(red[t], red[t + s2]);
        __syncthreads();
    }
    float ml = red[0];
    for (int i = t; i < NPTS; i += 256) {
        float d = mean_loss[(size_t)b * NPTS + i] - ml;
        float e = expf(-20.0f * d);
        float wts = 2.0f * (e / (1.0f + e));
        weight_out[(size_t)b * NPTS + i] = (wts > 0.5f) ? 1.0f : 0.0f;
    }
}

// ===========================================================================
// Kernel D: weighted Procrustes per batch (Horn quaternion)
// ===========================================================================
__device__ void jacobi4(double A[4][4], double V[4][4]) {
    for (int i = 0; i < 4; ++i)
        for (int j = 0; j < 4; ++j) V[i][j] = (i == j) ? 1.0 : 0.0;
    for (int sweep = 0; sweep < 30; ++sweep) {
        for (int p = 0; p < 3; ++p) for (int q = p + 1; q < 4; ++q) {
            double apq = A[p][q];
            if (fabs(apq) < 1e-30) continue;
            double theta = (A[q][q] - A[p][p]) / (2.0 * apq);
            double tt = (theta >= 0 ? 1.0 : -1.0) / (fabs(theta) + sqrt(theta * theta + 1.0));
            double c = 1.0 / sqrt(tt * tt + 1.0), s = tt * c;
            for (int k = 0; k < 4; ++k) {
                double akp = A[k][p], akq = A[k][q];
                A[k][p] = c * akp - s * akq;
                A[k][q] = s * akp + c * akq;
            }
            for (int k = 0; k < 4; ++k) {
                double apk = A[p][k], aqk = A[q][k];
                A[p][k] = c * apk - s * aqk;
                A[q][k] = s * apk + c * aqk;
            }
            for (int k = 0; k < 4; ++k) {
                double vkp = V[k][p], vkq = V[k][q];
                V[k][p] = c * vkp - s * vkq;
                V[k][q] = s * vkp + c * vkq;
            }
        }
    }
}

__global__ __launch_bounds__(256)
void procrustes_kernel(const float* __restrict__ src, const float* __restrict__ tgt,
                       const int* __restrict__ corres_i, const float* __restrict__ weight,
                       float* __restrict__ outR, float* __restrict__ outT)
{
    const int b = blockIdx.x;
    const int t = threadIdx.x;
    __shared__ float red[256][9];
    __shared__ float s_tw, s_mx[3], s_my[3];
    __shared__ float s_cov[9];

    float a0 = 0, a1 = 0, a2 = 0, a3 = 0, a4 = 0, a5 = 0, a6 = 0;
    for (int i = t; i < NPTS; i += 256) {
        float w = weight[(size_t)b * NPTS + i];
        float X0 = src[((size_t)b * 3 + 0) * NPTS + i];
        float X1 = src[((size_t)b * 3 + 1) * NPTS + i];
        float X2 = src[((size_t)b * 3 + 2) * NPTS + i];
        int c = corres_i[(size_t)b * NPTS + i];
        float Y0 = tgt[((size_t)b * 3 + 0) * NPTS + c];
        float Y1 = tgt[((size_t)b * 3 + 1) * NPTS + c];
        float Y2 = tgt[((size_t)b * 3 + 2) * NPTS + c];
        a0 += w;
        a1 += w * X0; a2 += w * X1; a3 += w * X2;
        a4 += w * Y0; a5 += w * Y1; a6 += w * Y2;
    }
    red[t][0] = a0; red[t][1] = a1; red[t][2] = a2; red[t][3] = a3;
    red[t][4] = a4; red[t][5] = a5; red[t][6] = a6; red[t][7] = 0; red[t][8] = 0;
    __syncthreads();
    for (int s2 = 128; s2 > 0; s2 >>= 1) {
        if (t < s2)
            for (int k = 0; k < 7; ++k) red[t][k] += red[t + s2][k];
        __syncthreads();
    }
    if (t == 0) {
        float tw = red[0][0];
        float itw = tw + 1e-7f;
        s_tw = tw;
        s_mx[0] = red[0][1] / itw; s_mx[1] = red[0][2] / itw; s_mx[2] = red[0][3] / itw;
        s_my[0] = red[0][4] / itw; s_my[1] = red[0][5] / itw; s_my[2] = red[0][6] / itw;
    }
    __syncthreads();
    const float twp = s_tw + 1e-7f;
    const float mx0 = s_mx[0], mx1 = s_mx[1], mx2 = s_mx[2];
    const float my0 = s_my[0], my1 = s_my[1], my2 = s_my[2];

    float cv[9] = {0,0,0,0,0,0,0,0,0};
    for (int i = t; i < NPTS; i += 256) {
        float w = weight[(size_t)b * NPTS + i];
        float nwn = w / twp;
        float X0 = src[((size_t)b * 3 + 0) * NPTS + i] - mx0;
        float X1 = src[((size_t)b * 3 + 1) * NPTS + i] - mx1;
        float X2 = src[((size_t)b * 3 + 2) * NPTS + i] - mx2;
        int c = corres_i[(size_t)b * NPTS + i];
        float Y0 = tgt[((size_t)b * 3 + 0) * NPTS + c] - my0;
        float Y1 = tgt[((size_t)b * 3 + 1) * NPTS + c] - my1;
        float Y2 = tgt[((size_t)b * 3 + 2) * NPTS + c] - my2;
        float b0 = nwn * X0, b1 = nwn * X1, b2 = nwn * X2;
        cv[0] += Y0 * b0; cv[1] += Y0 * b1; cv[2] += Y0 * b2;
        cv[3] += Y1 * b0; cv[4] += Y1 * b1; cv[5] += Y1 * b2;
        cv[6] += Y2 * b0; cv[7] += Y2 * b1; cv[8] += Y2 * b2;
    }
    __syncthreads();
    for (int k = 0; k < 9; ++k) red[t][k] = cv[k];
    __syncthreads();
    for (int s2 = 128; s2 > 0; s2 >>= 1) {
        if (t < s2)
            for (int k = 0; k < 9; ++k) red[t][k] += red[t + s2][k];
        __syncthreads();
    }
    if (t == 0) for (int k = 0; k < 9; ++k) s_cov[k] = red[0][k];
    __syncthreads();

    if (t == 0) {
        double cov[3][3];
        for (int i = 0; i < 3; ++i)
            for (int j = 0; j < 3; ++j) cov[i][j] = (double)s_cov[i * 3 + j];
        double S[3][3];
        for (int a = 0; a < 3; ++a)
            for (int bb = 0; bb < 3; ++bb) S[a][bb] = cov[bb][a];
        double N4[4][4];
        N4[0][0] = S[0][0] + S[1][1] + S[2][2];
        N4[0][1] = S[1][2] - S[2][1];
        N4[0][2] = S[2][0] - S[0][2];
        N4[0][3] = S[0][1] - S[1][0];
        N4[1][1] = S[0][0] - S[1][1] - S[2][2];
        N4[1][2] = S[0][1] + S[1][0];
        N4[1][3] = S[2][0] + S[0][2];
        N4[2][2] = -S[0][0] + S[1][1] - S[2][2];
        N4[2][3] = S[1][2] + S[2][1];
        N4[3][3] = -S[0][0] - S[1][1] + S[2][2];
        N4[1][0] = N4[0][1]; N4[2][0] = N4[0][2]; N4[3][0] = N4[0][3];
        N4[2][1] = N4[1][2]; N4[3][1] = N4[1][3]; N4[3][2] = N4[2][3];
        double V[4][4];
        jacobi4(N4, V);
        int best = 0; double bl = N4[0][0];
        for (int k = 1; k < 4; ++k) if (N4[k][k] > bl) { bl = N4[k][k]; best = k; }
        double q0 = V[0][best], qx = V[1][best], qy = V[2][best], qz = V[3][best];
        double nq = sqrt(q0 * q0 + qx * qx + qy * qy + qz * qz);
        q0 /= nq; qx /= nq; qy /= nq; qz /= nq;
        double Rm[3][3];
        Rm[0][0] = q0*q0 + qx*qx - qy*qy - qz*qz;
        Rm[0][1] = 2.0 * (qx*qy - q0*qz);
        Rm[0][2] = 2.0 * (qx*qz + q0*qy);
        Rm[1][0] = 2.0 * (qx*qy + q0*qz);
        Rm[1][1] = q0*q0 - qx*qx + qy*qy - qz*qz;
        Rm[1][2] = 2.0 * (qy*qz - q0*qx);
        Rm[2][0] = 2.0 * (qx*qz - q0*qy);
        Rm[2][1] = 2.0 * (qy*qz + q0*qx);
        Rm[2][2] = q0*q0 - qx*qx - qy*qy + qz*qz;
        double o1 = 0, o2 = 0;
        for (int i = 0; i < 3; ++i)
            for (int j = 0; j < 3; ++j) { o1 += Rm[i][j] * cov[i][j]; o2 += Rm[j][i] * cov[i][j]; }
        if (o2 > o1) {
            for (int i = 0; i < 3; ++i)
                for (int j = i + 1; j < 3; ++j) {
                    double tv = Rm[i][j]; Rm[i][j] = Rm[j][i]; Rm[j][i] = tv;
                }
        }
        float Rf[3][3];
        for (int i = 0; i < 3; ++i)
            for (int j = 0; j < 3; ++j) {
                Rf[i][j] = (float)Rm[i][j];
                outR[(size_t)b * 9 + i * 3 + j] = Rf[i][j];
            }
        float rm[3];
        float mxv[3] = {mx0, mx1, mx2};
        float myv[3] = {my0, my1, my2};
        for (int i = 0; i < 3; ++i)
            rm[i] = Rf[i][0] * mxv[0] + Rf[i][1] * mxv[1] + Rf[i][2] * mxv[2];
        for (int i = 0; i < 3; ++i)
            for (int j = 0; j < 3; ++j)
                outT[(size_t)b * 9 + i * 3 + j] = myv[j] - rm[i];
    }
}

// ===========================================================================
extern "C" void kernel_launch(void* const* d_in, const int* in_sizes, int n_in,
                              void* d_out, int out_size, void* d_ws, size_t ws_size,
                              hipStream_t stream)
{
    const float* se  = (const float*)d_in[0];
    const float* te  = (const float*)d_in[1];
    const float* src = (const float*)d_in[2];
    const float* tgt = (const float*)d_in[3];

    float* out  = (float*)d_out;
    float* outR = out;
    float* outT = out + 72;
    float* outC = out + 144;
    float* outW = out + 144 + BATCH * NPTS;

    char* wsb = (char*)d_ws;
    float* corr_tgt  = (float*)wsb;                                    // 196608 B
    int*   corres_i  = (int*)(wsb + 196608);                           // 65536 B
    float* mean_loss = (float*)(wsb + 262144);                         // 65536 B
    float* part      = (float*)(wsb + 327680);                         // 1 MB

    hipLaunchKernelGGL(score_kernel, dim3(BATCH * 32 * 2), dim3(256), 0, stream,
                       se, te, tgt, part);
    hipLaunchKernelGGL(merge_kernel, dim3(BATCH * NPTS / 256), dim3(256), 0, stream,
                       part, corr_tgt, corres_i, outC);
    hipLaunchKernelGGL(gfm_kernel, dim3(BATCH * 32), dim3(512), 0, stream,
                       src, corr_tgt, mean_loss);
    hipLaunchKernelGGL(weight_kernel, dim3(BATCH), dim3(256), 0, stream,
                       mean_loss, outW);
    hipLaunchKernelGGL(procrustes_kernel, dim3(BATCH), dim3(256), 0, stream,
                       src, tgt, corres_i, outW, outR, outT);
}

// Round 3
// 684.513 us; speedup vs baseline: 2.8040x; 1.5356x over previous
//
#include <hip/hip_runtime.h>
#include <math.h>

#define BATCH 8
#define DIM   512
#define NPTS  2048
#define KNN   10
#define NPAIR 45

typedef __attribute__((ext_vector_type(8))) short    bf16x8;
typedef __attribute__((ext_vector_type(4))) float    f32x4;
typedef __attribute__((ext_vector_type(4))) unsigned int u32x4;

__device__ inline unsigned short bf16_rne(float x) {
    unsigned int u = __float_as_uint(x);
    u += 0x7FFFu + ((u >> 16) & 1u);
    return (unsigned short)(u >> 16);
}
__device__ inline float bf16_to_f(unsigned short h) {
    return __uint_as_float(((unsigned int)h) << 16);
}

// ===========================================================================
// Kernel S: split se/te into 3 bf16 planes (h,m,l), transposed to [b][n][d].
// grid = 2 tensors * 8 b * 8 dtile * 32 ntile = 4096 blocks, 256 thr
// ===========================================================================
__global__ __launch_bounds__(256)
void split_kernel(const float* __restrict__ se, const float* __restrict__ te,
                  unsigned short* __restrict__ pA, unsigned short* __restrict__ pB)
{
    const int bid = blockIdx.x;
    const int tensor = bid >> 11;
    const int rr_ = bid & 2047;
    const int b  = rr_ >> 8;
    const int dt = (rr_ >> 5) & 7;
    const int nt = rr_ & 31;
    const float* srcp = (tensor == 0 ? se : te)
                        + ((size_t)b * DIM + dt * 64) * NPTS + nt * 64;
    unsigned short* dst = (tensor == 0 ? pA : pB);
    const size_t PL = (size_t)BATCH * NPTS * DIM;
    unsigned short* base = dst + (size_t)b * NPTS * DIM + (size_t)nt * 64 * DIM + dt * 64;

    __shared__ float T[64][65];
    const int t = threadIdx.x;
    {
        int r = t >> 4, c4 = t & 15;
        #pragma unroll
        for (int it = 0; it < 4; ++it) {
            int d = r + it * 16;
            float4 v = *(const float4*)&srcp[(size_t)d * NPTS + c4 * 4];
            T[d][c4 * 4 + 0] = v.x; T[d][c4 * 4 + 1] = v.y;
            T[d][c4 * 4 + 2] = v.z; T[d][c4 * 4 + 3] = v.w;
        }
    }
    __syncthreads();
    const int n  = t >> 2;
    const int d0 = (t & 3) * 16;
    unsigned short hh[16], mm[16], ll[16];
    #pragma unroll
    for (int j = 0; j < 16; ++j) {
        float a = T[d0 + j][n];
        unsigned short h = bf16_rne(a);
        float r1 = a - bf16_to_f(h);
        unsigned short m = bf16_rne(r1);
        float r2 = r1 - bf16_to_f(m);
        unsigned short l = bf16_rne(r2);
        hh[j] = h; mm[j] = m; ll[j] = l;
    }
    unsigned short* o = base + (size_t)n * DIM + d0;
    *(u32x4*)(o)            = *(u32x4*)&hh[0];
    *(u32x4*)(o + 8)        = *(u32x4*)&hh[8];
    *(u32x4*)(o + PL)       = *(u32x4*)&mm[0];
    *(u32x4*)(o + PL + 8)   = *(u32x4*)&mm[8];
    *(u32x4*)(o + 2*PL)     = *(u32x4*)&ll[0];
    *(u32x4*)(o + 2*PL + 8) = *(u32x4*)&ll[8];
}

// ===========================================================================
// Kernel A (MFMA): C = se^T te via 6 bf16 plane-products (K_eff=3072), fused
// online softmax(10000*C/sqrt(512)), argmax, sum(p*tgt). 128x128 tile, BK=64.
// grid = 8 b * 16 ntiles * 4 mchunks = 512 blocks, 256 thr (4 waves).
// Partial state per (row, chunk= mc*2+wm) -> part buffer (8 chunks).
// ===========================================================================
__global__ __launch_bounds__(256, 2)
void score_mfma(const unsigned short* __restrict__ pA, const unsigned short* __restrict__ pB,
                const float* __restrict__ tgt, float* __restrict__ part)
{
    const int bid = blockIdx.x;
    const int b     = bid >> 6;
    const int ntile = (bid >> 2) & 15;
    const int mc    = bid & 3;
    const int n0 = ntile * 128;
    const int t  = threadIdx.x;
    const int w  = t >> 6;
    const int l  = t & 63;
    const int wn = w >> 1, wm = w & 1;
    const int l15 = l & 15, l4 = l >> 4;

    __shared__ unsigned short As[128 * 64];   // [row][64k] swizzled, 16KB
    __shared__ unsigned short Bs[128 * 64];

    const size_t PL = (size_t)BATCH * NPTS * DIM;
    const int AIDX[6] = {0, 0, 1, 0, 1, 2};   // h,h,m,h,m,l
    const int BIDX[6] = {0, 1, 0, 2, 1, 0};   // h,m,h,l,m,h

    // staging map: linear slot s = qq*256+t -> (row, slot); element stored at
    // (row, slot) is global k-group slot^(row&7)   (XOR involution swizzle)
    int srow[4], sslot[4], skg[4], ldsoff[4];
    #pragma unroll
    for (int qq = 0; qq < 4; ++qq) {
        int s = qq * 256 + t;
        srow[qq] = s >> 3; sslot[qq] = s & 7;
        skg[qq] = sslot[qq] ^ (srow[qq] & 7);
        ldsoff[qq] = srow[qq] * 64 + sslot[qq] * 8;
    }
    // frag read offsets (constant): lane reads k-group (ks*4+l4) of its row
    int aroff[4], arxor[4], broff[4], brxor[4];
    #pragma unroll
    for (int i = 0; i < 4; ++i) {
        int ar = wn * 64 + i * 16 + l15;
        aroff[i] = ar * 64; arxor[i] = ar & 7;
        int br = wm * 64 + i * 16 + l15;
        broff[i] = br * 64; brxor[i] = br & 7;
    }

    float mx[16], sm[16], ax[16], ay[16], az[16]; int ag[16];
    #pragma unroll
    for (int si = 0; si < 16; ++si) {
        mx[si] = -3.402823466e38f; sm[si] = 0.f;
        ax[si] = 0.f; ay[si] = 0.f; az[si] = 0.f; ag[si] = 0;
    }

    const float sqd = sqrtf((float)DIM);
    const unsigned short* Ab = pA + (size_t)b * NPTS * DIM;
    const unsigned short* Bb = pB + (size_t)b * NPTS * DIM;

    for (int mt = 0; mt < 4; ++mt) {
        const int m0 = mc * 512 + mt * 128;
        f32x4 acc[4][4];
        #pragma unroll
        for (int i = 0; i < 4; ++i)
            #pragma unroll
            for (int j = 0; j < 4; ++j) acc[i][j] = (f32x4){0.f, 0.f, 0.f, 0.f};

        for (int q = 0; q < 6; ++q) {
            const unsigned short* Ap = Ab + (size_t)AIDX[q] * PL;
            const unsigned short* Bp = Bb + (size_t)BIDX[q] * PL;
            for (int k0 = 0; k0 < 512; k0 += 64) {
                __syncthreads();
                bf16x8 ra[4], rb[4];
                #pragma unroll
                for (int qq = 0; qq < 4; ++qq) {
                    ra[qq] = *(const bf16x8*)&Ap[(size_t)(n0 + srow[qq]) * DIM + k0 + skg[qq] * 8];
                    rb[qq] = *(const bf16x8*)&Bp[(size_t)(m0 + srow[qq]) * DIM + k0 + skg[qq] * 8];
                }
                #pragma unroll
                for (int qq = 0; qq < 4; ++qq) {
                    *(bf16x8*)&As[ldsoff[qq]] = ra[qq];
                    *(bf16x8*)&Bs[ldsoff[qq]] = rb[qq];
                }
                __syncthreads();
                #pragma unroll
                for (int ks = 0; ks < 2; ++ks) {
                    bf16x8 af[4], bfr[4];
                    #pragma unroll
                    for (int i = 0; i < 4; ++i) {
                        af[i]  = *(const bf16x8*)&As[aroff[i] + (((ks * 4 + l4) ^ arxor[i]) * 8)];
                        bfr[i] = *(const bf16x8*)&Bs[broff[i] + (((ks * 4 + l4) ^ brxor[i]) * 8)];
                    }
                    #pragma unroll
                    for (int i = 0; i < 4; ++i)
                        #pragma unroll
                        for (int j = 0; j < 4; ++j)
                            acc[i][j] = __builtin_amdgcn_mfma_f32_16x16x32_bf16(af[i], bfr[j], acc[i][j], 0, 0, 0);
                }
            }
        }
        // ---- fused online softmax/argmax epilogue for this m-tile ----
        float tg0[4], tg1[4], tg2[4];
        #pragma unroll
        for (int j = 0; j < 4; ++j) {
            int mcol = m0 + wm * 64 + j * 16 + l15;
            tg0[j] = tgt[((size_t)b * 3 + 0) * NPTS + mcol];
            tg1[j] = tgt[((size_t)b * 3 + 1) * NPTS + mcol];
            tg2[j] = tgt[((size_t)b * 3 + 2) * NPTS + mcol];
        }
        #pragma unroll
        for (int i = 0; i < 4; ++i) {
            #pragma unroll
            for (int r = 0; r < 4; ++r) {
                const int si = i * 4 + r;
                float u[4];
                float lm = -3.402823466e38f; int la = 0;
                #pragma unroll
                for (int j = 0; j < 4; ++j) {
                    float s  = acc[i][j][r] / sqd;
                    float uu = 10000.0f * s;
                    u[j] = uu;
                    if (uu > lm) { lm = uu; la = m0 + wm * 64 + j * 16 + l15; }
                }
                float nm = fmaxf(mx[si], lm);
                if (lm > mx[si]) ag[si] = la;
                float f = expf(mx[si] - nm);
                mx[si] = nm;
                float s_ = sm[si] * f, x_ = ax[si] * f, y_ = ay[si] * f, z_ = az[si] * f;
                #pragma unroll
                for (int j = 0; j < 4; ++j) {
                    float p = expf(u[j] - nm);
                    s_ += p; x_ += p * tg0[j]; y_ += p * tg1[j]; z_ += p * tg2[j];
                }
                sm[si] = s_; ax[si] = x_; ay[si] = y_; az[si] = z_;
            }
        }
    }

    // ---- butterfly merge across the 16 cols lanes (l15), keep l4 groups ----
    #pragma unroll
    for (int si = 0; si < 16; ++si) {
        for (int mask = 1; mask < 16; mask <<= 1) {
            float omx = __shfl_xor(mx[si], mask);
            float osm = __shfl_xor(sm[si], mask);
            float oax = __shfl_xor(ax[si], mask);
            float oay = __shfl_xor(ay[si], mask);
            float oaz = __shfl_xor(az[si], mask);
            int   oag = __shfl_xor(ag[si], mask);
            float nm = fmaxf(mx[si], omx);
            float f1 = expf(mx[si] - nm), f2 = expf(omx - nm);
            sm[si] = sm[si] * f1 + osm * f2;
            ax[si] = ax[si] * f1 + oax * f2;
            ay[si] = ay[si] * f1 + oay * f2;
            az[si] = az[si] * f1 + oaz * f2;
            ag[si] = (omx > mx[si]) ? oag : ((omx == mx[si]) ? min(ag[si], oag) : ag[si]);
            mx[si] = nm;
        }
    }
    if (l15 == 0) {
        const int chunk = mc * 2 + wm;
        #pragma unroll
        for (int i = 0; i < 4; ++i)
            #pragma unroll
            for (int r = 0; r < 4; ++r) {
                const int si = i * 4 + r;
                int nabs = n0 + wn * 64 + i * 16 + l4 * 4 + r;
                size_t o = (((size_t)b * NPTS + nabs) * 8 + chunk) * 8;
                part[o + 0] = mx[si]; part[o + 1] = sm[si];
                part[o + 2] = ax[si]; part[o + 3] = ay[si]; part[o + 4] = az[si];
                part[o + 5] = __int_as_float(ag[si]);
            }
    }
}

// ===========================================================================
// Kernel A2: merge 8 partial chunks per row (exact min-index tie rule)
// ===========================================================================
__global__ __launch_bounds__(256)
void merge8_kernel(const float* __restrict__ part, float* __restrict__ corr_tgt,
                   int* __restrict__ corres_i, float* __restrict__ corres_out)
{
    int r = blockIdx.x * 256 + threadIdx.x;
    float m = -3.402823466e38f, s = 0.f, x = 0.f, y = 0.f, z = 0.f; int a = 0x7fffffff;
    for (int c = 0; c < 8; ++c) {
        const float* p = &part[((size_t)r * 8 + c) * 8];
        float pm = p[0]; int pa = __float_as_int(p[5]);
        float nm = fmaxf(m, pm);
        float f1 = expf(m - nm), f2 = expf(pm - nm);
        s = s * f1 + p[1] * f2;
        x = x * f1 + p[2] * f2;
        y = y * f1 + p[3] * f2;
        z = z * f1 + p[4] * f2;
        if (pm > m) a = pa; else if (pm == m) a = min(a, pa);
        m = nm;
    }
    corr_tgt[(size_t)r * 3 + 0] = x / s;
    corr_tgt[(size_t)r * 3 + 1] = y / s;
    corr_tgt[(size_t)r * 3 + 2] = z / s;
    corres_i[r]   = a;
    corres_out[r] = (float)a;
}

// ===========================================================================
// FALLBACK score path (round-2, f32 VALU) — used if ws too small for planes
// ===========================================================================
#define SK_ROWS 64
#define SK_MT   256
#define SK_KC   32
#define SK_NMT  4
#define SK_NKC  16

__global__ __launch_bounds__(256)
void score_kernel_f32(const float* __restrict__ se, const float* __restrict__ te,
                      const float* __restrict__ tgt, float* __restrict__ part)
{
    const int bid = blockIdx.x;
    const int b   = bid >> 6;
    const int rt  = (bid >> 1) & 31;
    const int mcc = bid & 1;
    const int n0  = rt * SK_ROWS;
    const int t   = threadIdx.x;
    const int tr  = t >> 5;
    const int tc  = t & 31;

    __shared__ float As[SK_KC][SK_ROWS];
    __shared__ float Bs[SK_KC][SK_MT];
    __shared__ float tgtS[3][SK_MT];

    const float* A  = se + (size_t)b * DIM * NPTS;
    const float* Bp = te + (size_t)b * DIM * NPTS;
    const float sqd = sqrtf((float)DIM);

    float mx[8], sum[8], ax[8], ay[8], az[8];
    int   arg[8];
    #pragma unroll
    for (int r = 0; r < 8; ++r) {
        mx[r] = -3.402823466e38f; sum[r] = 0.f;
        ax[r] = 0.f; ay[r] = 0.f; az[r] = 0.f; arg[r] = 0;
    }

    for (int mt = 0; mt < SK_NMT; ++mt) {
        const int m0 = mcc * 1024 + mt * SK_MT;
        __syncthreads();
        for (int i = t; i < 3 * SK_MT; i += 256)
            tgtS[i >> 8][i & 255] = tgt[((size_t)b * 3 + (i >> 8)) * NPTS + m0 + (i & 255)];

        float acc[8][8];
        #pragma unroll
        for (int r = 0; r < 8; ++r)
            #pragma unroll
            for (int c = 0; c < 8; ++c) acc[r][c] = 0.f;

        for (int kc = 0; kc < SK_NKC; ++kc) {
            const int k0 = kc * SK_KC;
            __syncthreads();
            #pragma unroll
            for (int p = 0; p < 2; ++p) {
                int id = t + p * 256;
                int kk = id >> 4, c4 = id & 15;
                float4 v = *(const float4*)&A[(size_t)(k0 + kk) * NPTS + n0 + c4 * 4];
                *(float4*)&As[kk][c4 * 4] = v;
            }
            #pragma unroll
            for (int p = 0; p < 8; ++p) {
                int id = t + p * 256;
                int kk = id >> 6, c4 = id & 63;
                float4 v = *(const float4*)&Bp[(size_t)(k0 + kk) * NPTS + m0 + c4 * 4];
                *(float4*)&Bs[kk][c4 * 4] = v;
            }
            __syncthreads();
            #pragma unroll
            for (int kk = 0; kk < SK_KC; ++kk) {
                float4 af0 = *(const float4*)&As[kk][tr * 8];
                float4 af1 = *(const float4*)&As[kk][tr * 8 + 4];
                float a0[8] = {af0.x, af0.y, af0.z, af0.w, af1.x, af1.y, af1.z, af1.w};
                float2 bb[4];
                #pragma unroll
                for (int jj = 0; jj < 4; ++jj)
                    bb[jj] = *(const float2*)&Bs[kk][2 * tc + jj * 64];
                #pragma unroll
                for (int r = 0; r < 8; ++r) {
                    #pragma unroll
                    for (int jj = 0; jj < 4; ++jj) {
                        acc[r][2 * jj]     += a0[r] * bb[jj].x;
                        acc[r][2 * jj + 1] += a0[r] * bb[jj].y;
                    }
                }
            }
        }
        #pragma unroll
        for (int r = 0; r < 8; ++r) {
            float u[8];
            float lm = -3.402823466e38f; int la = 0;
            #pragma unroll
            for (int jj = 0; jj < 4; ++jj) {
                #pragma unroll
                for (int e = 0; e < 2; ++e) {
                    int ci = 2 * jj + e;
                    float s  = acc[r][ci] / sqd;
                    float uu = 10000.0f * s;
                    u[ci] = uu;
                    if (uu > lm) { lm = uu; la = m0 + 2 * tc + jj * 64 + e; }
                }
            }
            float nm = fmaxf(mx[r], lm);
            if (lm > mx[r]) arg[r] = la;
            float f = expf(mx[r] - nm);
            mx[r] = nm;
            float s_ = sum[r] * f, x_ = ax[r] * f, y_ = ay[r] * f, z_ = az[r] * f;
            #pragma unroll
            for (int jj = 0; jj < 4; ++jj) {
                #pragma unroll
                for (int e = 0; e < 2; ++e) {
                    int ci = 2 * jj + e;
                    float p = expf(u[ci] - nm);
                    int cc = 2 * tc + jj * 64 + e;
                    s_ += p;
                    x_ += p * tgtS[0][cc];
                    y_ += p * tgtS[1][cc];
                    z_ += p * tgtS[2][cc];
                }
            }
            sum[r] = s_; ax[r] = x_; ay[r] = y_; az[r] = z_;
        }
    }

    #pragma unroll
    for (int r = 0; r < 8; ++r) {
        for (int mask = 1; mask < 32; mask <<= 1) {
            float omx  = __shfl_xor(mx[r],  mask);
            float osum = __shfl_xor(sum[r], mask);
            float oax  = __shfl_xor(ax[r],  mask);
            float oay  = __shfl_xor(ay[r],  mask);
            float oaz  = __shfl_xor(az[r],  mask);
            int   oarg = __shfl_xor(arg[r], mask);
            float nm = fmaxf(mx[r], omx);
            float f1 = expf(mx[r] - nm), f2 = expf(omx - nm);
            sum[r] = sum[r] * f1 + osum * f2;
            ax[r]  = ax[r]  * f1 + oax  * f2;
            ay[r]  = ay[r]  * f1 + oay  * f2;
            az[r]  = az[r]  * f1 + oaz  * f2;
            arg[r] = (omx > mx[r]) ? oarg : ((omx == mx[r]) ? min(arg[r], oarg) : arg[r]);
            mx[r]  = nm;
        }
    }
    if (tc == 0) {
        #pragma unroll
        for (int r = 0; r < 8; ++r) {
            int row = n0 + tr * 8 + r;
            size_t o = (((size_t)b * NPTS + row) * 2 + mcc) * 8;
            part[o + 0] = mx[r];  part[o + 1] = sum[r];
            part[o + 2] = ax[r];  part[o + 3] = ay[r];  part[o + 4] = az[r];
            part[o + 5] = __int_as_float(arg[r]);
        }
    }
}

__global__ __launch_bounds__(256)
void merge2_kernel(const float* __restrict__ part, float* __restrict__ corr_tgt,
                   int* __restrict__ corres_i, float* __restrict__ corres_out)
{
    int r = blockIdx.x * 256 + threadIdx.x;
    size_t o0 = ((size_t)r * 2 + 0) * 8;
    size_t o1 = ((size_t)r * 2 + 1) * 8;
    float m1 = part[o0], s1 = part[o0 + 1], x1 = part[o0 + 2], y1 = part[o0 + 3], z1 = part[o0 + 4];
    int   a1 = __float_as_int(part[o0 + 5]);
    float m2 = part[o1], s2 = part[o1 + 1], x2 = part[o1 + 2], y2 = part[o1 + 3], z2 = part[o1 + 4];
    int   a2 = __float_as_int(part[o1 + 5]);
    float nm = fmaxf(m1, m2);
    float f1 = expf(m1 - nm), f2 = expf(m2 - nm);
    float s = s1 * f1 + s2 * f2;
    float x = x1 * f1 + x2 * f2;
    float y = y1 * f1 + y2 * f2;
    float z = z1 * f1 + z2 * f2;
    int a = (m2 > m1) ? a2 : a1;
    corr_tgt[(size_t)r * 3 + 0] = x / s;
    corr_tgt[(size_t)r * 3 + 1] = y / s;
    corr_tgt[(size_t)r * 3 + 2] = z / s;
    corres_i[r]   = a;
    corres_out[r] = (float)a;
}

// ===========================================================================
// Kernel B: GFM (unchanged from round 2, passing)
// ===========================================================================
#define GF_N  64
#define GF_C  8
#define GF_CS 256

__global__ __launch_bounds__(512)
void gfm_kernel(const float* __restrict__ src, const float* __restrict__ corr_tgt,
                float* __restrict__ mean_loss)
{
    const int b  = blockIdx.x >> 5;
    const int n0 = (blockIdx.x & 31) * GF_N;
    const int t  = threadIdx.x;
    __shared__ float4 P4[NPTS];
    __shared__ float  CT[NPTS][3];
    __shared__ float  Lw[GF_N][GF_C][KNN];
    __shared__ int    Li[GF_N][GF_C][KNN];

    for (int i = t; i < NPTS; i += 512) {
        float x = src[((size_t)b * 3 + 0) * NPTS + i];
        float y = src[((size_t)b * 3 + 1) * NPTS + i];
        float z = src[((size_t)b * 3 + 2) * NPTS + i];
        P4[i] = make_float4(x, y, z, x * x + y * y + z * z);
        size_t o = ((size_t)b * NPTS + i) * 3;
        CT[i][0] = corr_tgt[o]; CT[i][1] = corr_tgt[o + 1]; CT[i][2] = corr_tgt[o + 2];
    }
    __syncthreads();

    {
        const int nl = t & 63;
        const int c  = t >> 6;
        const int n  = n0 + nl;
        float4 pn = P4[n];
        float wl[KNN]; int il[KNN];
        #pragma unroll
        for (int k = 0; k < KNN; ++k) { wl[k] = -1.f; il[k] = 0; }
        const int mstart = c * GF_CS;
        for (int mm = 0; mm < GF_CS; ++mm) {
            int m = mstart + mm;
            float4 pm = P4[m];
            float dot = pn.x * pm.x + pn.y * pm.y + pn.z * pm.z;
            float d2  = (pn.w + pm.w) - 2.0f * dot;
            if (d2 < 0.f) d2 = 0.f;
            float w = expf(-d2 * 0.5f);
            if (w > wl[KNN - 1]) {
                float cw = w; int ci = m;
                #pragma unroll
                for (int k = 0; k < KNN; ++k) {
                    if (cw > wl[k]) {
                        float tv = wl[k]; wl[k] = cw; cw = tv;
                        int ti = il[k]; il[k] = ci; ci = ti;
                    }
                }
            }
        }
        #pragma unroll
        for (int k = 0; k < KNN; ++k) { Lw[nl][c][k] = wl[k]; Li[nl][c][k] = il[k]; }
    }
    __syncthreads();

    if (t < GF_N) {
        const int n = n0 + t;
        int hp[GF_C];
        #pragma unroll
        for (int c = 0; c < GF_C; ++c) hp[c] = 0;
        int il[KNN];
        #pragma unroll
        for (int k = 0; k < KNN; ++k) {
            int bc = -1; float bw = 0.f;
            #pragma unroll
            for (int c = 0; c < GF_C; ++c) {
                if (hp[c] < KNN) {
                    float w = Lw[t][c][hp[c]];
                    if (bc < 0 || w > bw) { bw = w; bc = c; }
                }
            }
            il[k] = Li[t][bc][hp[bc]];
            hp[bc]++;
        }

        float4 pn = P4[n];
        const float pnx = pn.x, pny = pn.y, pnz = pn.z;
        float kx[KNN], ky[KNN], kz[KNN], tx[KNN], ty[KNN], tz[KNN];
        #pragma unroll
        for (int k = 0; k < KNN; ++k) {
            float4 pk = P4[il[k]];
            kx[k] = pk.x; ky[k] = pk.y; kz[k] = pk.z;
            tx[k] = CT[il[k]][0]; ty[k] = CT[il[k]][1]; tz[k] = CT[il[k]][2];
        }
        const float cnx = CT[n][0], cny = CT[n][1], cnz = CT[n][2];

        float ls[NPAIR], rg[NPAIR];
        int q = 0;
        #pragma unroll
        for (int i = 0; i < KNN - 1; ++i) {
            #pragma unroll
            for (int j = i + 1; j < KNN; ++j) {
                float e1x = kx[i] - pnx, e1y = ky[i] - pny, e1z = kz[i] - pnz;
                float e2x = kx[j] - pnx, e2y = ky[j] - pny, e2z = kz[j] - pnz;
                float cx = e1y * e2z - e1z * e2y;
                float cy = e1z * e2x - e1x * e2z;
                float cz = e1x * e2y - e1y * e2x;
                float as_ = 0.5f * sqrtf(cx * cx + cy * cy + cz * cz);
                float f1x = tx[i] - cnx, f1y = ty[i] - cny, f1z = tz[i] - cnz;
                float f2x = tx[j] - cnx, f2y = ty[j] - cny, f2z = tz[j] - cnz;
                float gx = f1y * f2z - f1z * f2y;
                float gy = f1z * f2x - f1x * f2z;
                float gz = f1x * f2y - f1y * f2x;
                float at_ = 0.5f * sqrtf(gx * gx + gy * gy + gz * gz);
                float tl2 = at_ + 1e-6f;
                float dd  = as_ - tl2;
                float e2_ = 1e-6f * 1e-6f;
                float num = (e2_ + e2_) + dd * dd;
                float den = (1e-6f + 1e-6f) + (as_ + tl2);
                ls[q] = num / den;
                rg[q] = sqrtf(num);
                ++q;
            }
        }
        float srt[NPAIR], tot[NPAIR], tmp[NPAIR];
        for (int k = 0; k < NPAIR; ++k) srt[k] = ls[k];
        for (int i = 1; i < NPAIR; ++i) {
            float key = srt[i]; int j = i - 1;
            while (j >= 0 && srt[j] > key) { srt[j + 1] = srt[j]; --j; }
            srt[j + 1] = key;
        }
        for (int k = 0; k < NPAIR; ++k) { tot[k] = srt[k] + 0.1f * rg[k]; tmp[k] = tot[k]; }
        for (int i = 1; i < NPAIR; ++i) {
            float key = tmp[i]; int j = i - 1;
            while (j >= 0 && tmp[j] > key) { tmp[j + 1] = tmp[j]; --j; }
            tmp[j + 1] = key;
        }
        float thr = 3.0f * tmp[22];
        float accv = 0.f;
        for (int k = 0; k < KNN; ++k) {
            float v = tot[k];
            v = (v > thr) ? 0.0f : v;
            accv += sqrtf(v + 1e-6f);
        }
        mean_loss[(size_t)b * NPTS + n] = accv / 10.0f;
    }
}

// ===========================================================================
// Kernel C: per-batch min + binary weight
// ===========================================================================
__global__ __launch_bounds__(256)
void weight_kernel(const float* __restrict__ mean_loss, float* __restrict__ weight_out)
{
    const int b = blockIdx.x;
    const int t = threadIdx.x;
    __shared__ float red[256];
    float mn = 3.402823466e38f;
    for (int i = t; i < NPTS; i += 256)
        mn = fminf(mn, mean_loss[(size_t)b * NPTS + i]);
    red[t] = mn; __syncthreads();
    for (int s2 = 128; s2 > 0; s2 >>= 1) {
        if (t < s2) red[t] = fminf(red[t], red[t + s2]);
        __syncthreads();
    }
    float ml = red[0];
    for (int i = t; i < NPTS; i += 256) {
        float d = mean_loss[(size_t)b * NPTS + i] - ml;
        float e = expf(-20.0f * d);
        float wts = 2.0f * (e / (1.0f + e));
        weight_out[(size_t)b * NPTS + i] = (wts > 0.5f) ? 1.0f : 0.0f;
    }
}

// ===========================================================================
// Kernel D: weighted Procrustes per batch (Horn quaternion)
// ===========================================================================
__device__ void jacobi4(double A[4][4], double V[4][4]) {
    for (int i = 0; i < 4; ++i)
        for (int j = 0; j < 4; ++j) V[i][j] = (i == j) ? 1.0 : 0.0;
    for (int sweep = 0; sweep < 12; ++sweep) {
        for (int p = 0; p < 3; ++p) for (int q = p + 1; q < 4; ++q) {
            double apq = A[p][q];
            if (fabs(apq) < 1e-30) continue;
            double theta = (A[q][q] - A[p][p]) / (2.0 * apq);
            double tt = (theta >= 0 ? 1.0 : -1.0) / (fabs(theta) + sqrt(theta * theta + 1.0));
            double c = 1.0 / sqrt(tt * tt + 1.0), s = tt * c;
            for (int k = 0; k < 4; ++k) {
                double akp = A[k][p], akq = A[k][q];
                A[k][p] = c * akp - s * akq;
                A[k][q] = s * akp + c * akq;
            }
            for (int k = 0; k < 4; ++k) {
                double apk = A[p][k], aqk = A[q][k];
                A[p][k] = c * apk - s * aqk;
                A[q][k] = s * apk + c * aqk;
            }
            for (int k = 0; k < 4; ++k) {
                double vkp = V[k][p], vkq = V[k][q];
                V[k][p] = c * vkp - s * vkq;
                V[k][q] = s * vkp + c * vkq;
            }
        }
    }
}

__global__ __launch_bounds__(256)
void procrustes_kernel(const float* __restrict__ src, const float* __restrict__ tgt,
                       const int* __restrict__ corres_i, const float* __restrict__ weight,
                       float* __restrict__ outR, float* __restrict__ outT)
{
    const int b = blockIdx.x;
    const int t = threadIdx.x;
    __shared__ float red[256][9];
    __shared__ float s_tw, s_mx[3], s_my[3];
    __shared__ float s_cov[9];

    float a0 = 0, a1 = 0, a2 = 0, a3 = 0, a4 = 0, a5 = 0, a6 = 0;
    for (int i = t; i < NPTS; i += 256) {
        float w = weight[(size_t)b * NPTS + i];
        float X0 = src[((size_t)b * 3 + 0) * NPTS + i];
        float X1 = src[((size_t)b * 3 + 1) * NPTS + i];
        float X2 = src[((size_t)b * 3 + 2) * NPTS + i];
        int c = corres_i[(size_t)b * NPTS + i];
        float Y0 = tgt[((size_t)b * 3 + 0) * NPTS + c];
        float Y1 = tgt[((size_t)b * 3 + 1) * NPTS + c];
        float Y2 = tgt[((size_t)b * 3 + 2) * NPTS + c];
        a0 += w;
        a1 += w * X0; a2 += w * X1; a3 += w * X2;
        a4 += w * Y0; a5 += w * Y1; a6 += w * Y2;
    }
    red[t][0] = a0; red[t][1] = a1; red[t][2] = a2; red[t][3] = a3;
    red[t][4] = a4; red[t][5] = a5; red[t][6] = a6; red[t][7] = 0; red[t][8] = 0;
    __syncthreads();
    for (int s2 = 128; s2 > 0; s2 >>= 1) {
        if (t < s2)
            for (int k = 0; k < 7; ++k) red[t][k] += red[t + s2][k];
        __syncthreads();
    }
    if (t == 0) {
        float tw = red[0][0];
        float itw = tw + 1e-7f;
        s_tw = tw;
        s_mx[0] = red[0][1] / itw; s_mx[1] = red[0][2] / itw; s_mx[2] = red[0][3] / itw;
        s_my[0] = red[0][4] / itw; s_my[1] = red[0][5] / itw; s_my[2] = red[0][6] / itw;
    }
    __syncthreads();
    const float twp = s_tw + 1e-7f;
    const float mx0 = s_mx[0], mx1 = s_mx[1], mx2 = s_mx[2];
    const float my0 = s_my[0], my1 = s_my[1], my2 = s_my[2];

    float cv[9] = {0,0,0,0,0,0,0,0,0};
    for (int i = t; i < NPTS; i += 256) {
        float w = weight[(size_t)b * NPTS + i];
        float nwn = w / twp;
        float X0 = src[((size_t)b * 3 + 0) * NPTS + i] - mx0;
        float X1 = src[((size_t)b * 3 + 1) * NPTS + i] - mx1;
        float X2 = src[((size_t)b * 3 + 2) * NPTS + i] - mx2;
        int c = corres_i[(size_t)b * NPTS + i];
        float Y0 = tgt[((size_t)b * 3 + 0) * NPTS + c] - my0;
        float Y1 = tgt[((size_t)b * 3 + 1) * NPTS + c] - my1;
        float Y2 = tgt[((size_t)b * 3 + 2) * NPTS + c] - my2;
        float b0 = nwn * X0, b1 = nwn * X1, b2 = nwn * X2;
        cv[0] += Y0 * b0; cv[1] += Y0 * b1; cv[2] += Y0 * b2;
        cv[3] += Y1 * b0; cv[4] += Y1 * b1; cv[5] += Y1 * b2;
        cv[6] += Y2 * b0; cv[7] += Y2 * b1; cv[8] += Y2 * b2;
    }
    __syncthreads();
    for (int k = 0; k < 9; ++k) red[t][k] = cv[k];
    __syncthreads();
    for (int s2 = 128; s2 > 0; s2 >>= 1) {
        if (t < s2)
            for (int k = 0; k < 9; ++k) red[t][k] += red[t + s2][k];
        __syncthreads();
    }
    if (t == 0) for (int k = 0; k < 9; ++k) s_cov[k] = red[0][k];
    __syncthreads();

    if (t == 0) {
        double cov[3][3];
        for (int i = 0; i < 3; ++i)
            for (int j = 0; j < 3; ++j) cov[i][j] = (double)s_cov[i * 3 + j];
        double S[3][3];
        for (int a = 0; a < 3; ++a)
            for (int bb = 0; bb < 3; ++bb) S[a][bb] = cov[bb][a];
        double N4[4][4];
        N4[0][0] = S[0][0] + S[1][1] + S[2][2];
        N4[0][1] = S[1][2] - S[2][1];
        N4[0][2] = S[2][0] - S[0][2];
        N4[0][3] = S[0][1] - S[1][0];
        N4[1][1] = S[0][0] - S[1][1] - S[2][2];
        N4[1][2] = S[0][1] + S[1][0];
        N4[1][3] = S[2][0] + S[0][2];
        N4[2][2] = -S[0][0] + S[1][1] - S[2][2];
        N4[2][3] = S[1][2] + S[2][1];
        N4[3][3] = -S[0][0] - S[1][1] + S[2][2];
        N4[1][0] = N4[0][1]; N4[2][0] = N4[0][2]; N4[3][0] = N4[0][3];
        N4[2][1] = N4[1][2]; N4[3][1] = N4[1][3]; N4[3][2] = N4[2][3];
        double V[4][4];
        jacobi4(N4, V);
        int best = 0; double bl = N4[0][0];
        for (int k = 1; k < 4; ++k) if (N4[k][k] > bl) { bl = N4[k][k]; best = k; }
        double q0 = V[0][best], qx = V[1][best], qy = V[2][best], qz = V[3][best];
        double nq = sqrt(q0 * q0 + qx * qx + qy * qy + qz * qz);
        q0 /= nq; qx /= nq; qy /= nq; qz /= nq;
        double Rm[3][3];
        Rm[0][0] = q0*q0 + qx*qx - qy*qy - qz*qz;
        Rm[0][1] = 2.0 * (qx*qy - q0*qz);
        Rm[0][2] = 2.0 * (qx*qz + q0*qy);
        Rm[1][0] = 2.0 * (qx*qy + q0*qz);
        Rm[1][1] = q0*q0 - qx*qx + qy*qy - qz*qz;
        Rm[1][2] = 2.0 * (qy*qz - q0*qx);
        Rm[2][0] = 2.0 * (qx*qz - q0*qy);
        Rm[2][1] = 2.0 * (qy*qz + q0*qx);
        Rm[2][2] = q0*q0 - qx*qx - qy*qy + qz*qz;
        double o1 = 0, o2 = 0;
        for (int i = 0; i < 3; ++i)
            for (int j = 0; j < 3; ++j) { o1 += Rm[i][j] * cov[i][j]; o2 += Rm[j][i] * cov[i][j]; }
        if (o2 > o1) {
            for (int i = 0; i < 3; ++i)
                for (int j = i + 1; j < 3; ++j) {
                    double tv = Rm[i][j]; Rm[i][j] = Rm[j][i]; Rm[j][i] = tv;
                }
        }
        float Rf[3][3];
        for (int i = 0; i < 3; ++i)
            for (int j = 0; j < 3; ++j) {
                Rf[i][j] = (float)Rm[i][j];
                outR[(size_t)b * 9 + i * 3 + j] = Rf[i][j];
            }
        float rm[3];
        float mxv[3] = {mx0, mx1, mx2};
        float myv[3] = {my0, my1, my2};
        for (int i = 0; i < 3; ++i)
            rm[i] = Rf[i][0] * mxv[0] + Rf[i][1] * mxv[1] + Rf[i][2] * mxv[2];
        for (int i = 0; i < 3; ++i)
            for (int j = 0; j < 3; ++j)
                outT[(size_t)b * 9 + i * 3 + j] = myv[j] - rm[i];
    }
}

// ===========================================================================
extern "C" void kernel_launch(void* const* d_in, const int* in_sizes, int n_in,
                              void* d_out, int out_size, void* d_ws, size_t ws_size,
                              hipStream_t stream)
{
    const float* se  = (const float*)d_in[0];
    const float* te  = (const float*)d_in[1];
    const float* src = (const float*)d_in[2];
    const float* tgt = (const float*)d_in[3];

    float* out  = (float*)d_out;
    float* outR = out;
    float* outT = out + 72;
    float* outC = out + 144;
    float* outW = out + 144 + BATCH * NPTS;

    char* wsb = (char*)d_ws;
    float* corr_tgt  = (float*)wsb;                                    // 196608 B
    int*   corres_i  = (int*)(wsb + 196608);                           // 65536 B
    float* mean_loss = (float*)(wsb + 262144);                         // 65536 B
    float* part      = (float*)(wsb + 327680);                         // 4 MB (8 chunks)

    const size_t PLANES_OFF = 4521984;                                 // 327680 + 4194304
    const size_t PL_BYTES   = (size_t)3 * BATCH * NPTS * DIM * 2;      // 50331648
    const size_t NEED       = PLANES_OFF + 2 * PL_BYTES;               // 105185280

    if (ws_size >= NEED) {
        unsigned short* pA = (unsigned short*)(wsb + PLANES_OFF);
        unsigned short* pB = (unsigned short*)(wsb + PLANES_OFF + PL_BYTES);
        hipLaunchKernelGGL(split_kernel, dim3(4096), dim3(256), 0, stream, se, te, pA, pB);
        hipLaunchKernelGGL(score_mfma, dim3(512), dim3(256), 0, stream, pA, pB, tgt, part);
        hipLaunchKernelGGL(merge8_kernel, dim3(BATCH * NPTS / 256), dim3(256), 0, stream,
                           part, corr_tgt, corres_i, outC);
    } else {
        hipLaunchKernelGGL(score_kernel_f32, dim3(BATCH * 32 * 2), dim3(256), 0, stream,
                           se, te, tgt, part);
        hipLaunchKernelGGL(merge2_kernel, dim3(BATCH * NPTS / 256), dim3(256), 0, stream,
                           part, corr_tgt, corres_i, outC);
    }
    hipLaunchKernelGGL(gfm_kernel, dim3(BATCH * 32), dim3(512), 0, stream,
                       src, corr_tgt, mean_loss);
    hipLaunchKernelGGL(weight_kernel, dim3(BATCH), dim3(256), 0, stream,
                       mean_loss, outW);
    hipLaunchKernelGGL(procrustes_kernel, dim3(BATCH), dim3(256), 0, stream,
                       src, tgt, corres_i, outW, outR, outT);
}